// Round 5
// baseline (499.357 us; speedup 1.0000x reference)
//
#include <hip/hip_runtime.h>
#include <cstdint>
#include <cstddef>

#define BATCH 8192
#define IN_F 1024
#define OUT_F 1024
#define NSPL 9               // 1 base channel + 8 spline basis channels
#define KDIM (IN_F * NSPL)   // 9216
// K-ordering is PLANAR: k = r*1024 + i  (both A and Wt use it; GEMM is
// permutation-agnostic as long as the two sides match).

typedef __bf16 bf16x8 __attribute__((ext_vector_type(8)));
typedef __bf16 bf16x4 __attribute__((ext_vector_type(4)));
typedef float f32x4 __attribute__((ext_vector_type(4)));

// async global->LDS, 16B/lane; LDS dest is wave-uniform base + lane*16
__device__ __forceinline__ void g2l16(const void* g, void* l) {
  __builtin_amdgcn_global_load_lds(
      (__attribute__((address_space(1))) void*)(g),
      (__attribute__((address_space(3))) void*)(l),
      16, 0, 0);
}

// ---------------------------------------------------------------------------
// Kernel 1: combined weight, planar: Wt[o][r*1024+i] bf16.
//   r=0: base_weight[o][i]; r=1..8: spline_weight[i][r-1][o]*spline_scaler[i][o]
// 64o x 16i LDS tile -> coalesced 256B input bursts; writes in 32B segments.
// ---------------------------------------------------------------------------
__global__ __launch_bounds__(256) void build_w(const float* __restrict__ bw,
                                               const float* __restrict__ sw,
                                               const float* __restrict__ sc,
                                               __bf16* __restrict__ Wt) {
  __shared__ float s_sw[16 * 8 * 64];  // [i][r][oo] 32KB
  __shared__ float s_sc[16 * 64];      // [i][oo]     4KB
  __shared__ float s_bw[64 * 16];      // [oo][i]     4KB
  const int tid = threadIdx.x;
  const int o0 = (blockIdx.x & 15) * 64;
  const int i0 = (blockIdx.x >> 4) * 16;

#pragma unroll
  for (int it = 0; it < 32; ++it) {   // sw: 8192 floats
    const int t = it * 256 + tid;
    const int i = t >> 9, r = (t >> 6) & 7, oo = t & 63;
    s_sw[t] = sw[((size_t)(i0 + i) * 8 + r) * OUT_F + o0 + oo];
  }
#pragma unroll
  for (int it = 0; it < 4; ++it) {    // sc: 1024 floats
    const int t = it * 256 + tid;
    const int i = t >> 6, oo = t & 63;
    s_sc[t] = sc[(size_t)(i0 + i) * OUT_F + o0 + oo];
  }
#pragma unroll
  for (int it = 0; it < 4; ++it) {    // bw: 1024 floats
    const int t = it * 256 + tid;
    const int oo = t >> 4, ii = t & 15;
    s_bw[t] = bw[(size_t)(o0 + oo) * IN_F + i0 + ii];
  }
  __syncthreads();

  // thread t: oo = t>>2, ig = t&3 -> 4 consecutive i's; 4 lanes = 32B contiguous
  const int oo = tid >> 2;
  const int ig = (tid & 3) * 4;
  __bf16* orow = Wt + (size_t)(o0 + oo) * KDIM;

  {  // r=0 plane: base weight
    bf16x4 v;
#pragma unroll
    for (int e = 0; e < 4; ++e) v[e] = (__bf16)s_bw[oo * 16 + ig + e];
    *(bf16x4*)(orow + i0 + ig) = v;
  }
#pragma unroll
  for (int r = 0; r < 8; ++r) {  // spline planes
    bf16x4 v;
#pragma unroll
    for (int e = 0; e < 4; ++e) {
      const int i = ig + e;
      v[e] = (__bf16)(s_sw[i * 512 + r * 64 + oo] * s_sc[i * 64 + oo]);
    }
    *(bf16x4*)(orow + (r + 1) * 1024 + i0 + ig) = v;
  }
}

// ---------------------------------------------------------------------------
// Kernel 2: augmented activations, planar: A[b][r*1024+i] bf16.
//   r=0: silu(x); r=1..8: closed-form uniform cubic B-spline basis.
// LDS-free (round-3 version's 18B-stride ds_write_b16 staging was 4-way
// bank-conflicted): thread reads float4 of x, writes 9 coalesced bf16x4.
// ---------------------------------------------------------------------------
__global__ __launch_bounds__(256) void build_a(const float* __restrict__ x,
                                               __bf16* __restrict__ A) {
  const int b = blockIdx.x;
  const int tid = threadIdx.x;
  const int i0 = tid * 4;
  const float4 v4 = ((const float4*)(x + (size_t)b * IN_F))[tid];
  const float vs[4] = {v4.x, v4.y, v4.z, v4.w};

  float w[NSPL][4];
#pragma unroll
  for (int r = 0; r < NSPL; ++r)
#pragma unroll
    for (int e = 0; e < 4; ++e) w[r][e] = 0.f;

#pragma unroll
  for (int e = 0; e < 4; ++e) {
    const float v = vs[e];
    w[0][e] = v / (1.f + __expf(-v));  // silu
    // uniform cubic B-spline: knots t_j = -2.2 + 0.4*j, j=0..11; cells 0..10
    const float p = (v + 2.2f) * 2.5f;
    const int cell = (int)floorf(p);
    if (cell >= 0 && cell <= 10 && v < 2.2f) {
      const float t = p - (float)cell;
      const float t2 = t * t, t3 = t2 * t;
      const float omt = 1.f - t;
      const float b0 = (1.f / 6.f) * omt * omt * omt;
      const float b1 = (1.f / 6.f) * (3.f * t3 - 6.f * t2 + 4.f);
      const float b2 = (1.f / 6.f) * (-3.f * t3 + 3.f * t2 + 3.f * t + 1.f);
      const float b3 = (1.f / 6.f) * t3;
      const int j0 = cell - 3;
      if (j0 + 0 >= 0 && j0 + 0 <= 7) w[1 + j0 + 0][e] = b0;
      if (j0 + 1 >= 0 && j0 + 1 <= 7) w[1 + j0 + 1][e] = b1;
      if (j0 + 2 >= 0 && j0 + 2 <= 7) w[1 + j0 + 2][e] = b2;
      if (j0 + 3 >= 0 && j0 + 3 <= 7) w[1 + j0 + 3][e] = b3;
    }
  }

  __bf16* dst = A + (size_t)b * KDIM;
#pragma unroll
  for (int r = 0; r < NSPL; ++r) {
    bf16x4 v;
#pragma unroll
    for (int e = 0; e < 4; ++e) v[e] = (__bf16)w[r][e];
    *(bf16x4*)(dst + r * 1024 + i0) = v;  // 8B/lane, fully coalesced per plane
  }
}

// ---------------------------------------------------------------------------
// Kernel 3 (reverted to round-3 exactly — its 192us/806TF is this structure's
// operating point; round-4 split-K showed occupancy is register-capped at
// 8 waves/CU (64 AGPR acc + 84 VGPR > 128-reg bin), so more blocks don't help).
// GEMM out[8192][1024] = A[8192][9216] * Wt[1024][9216]^T; BK=64 as two
// proven 128x32 sub-tiles; 128x128 tile, 4 waves, 4x4 mfma 16x16x32 bf16.
// ---------------------------------------------------------------------------
__global__ __launch_bounds__(256) void gemm_bt(const __bf16* __restrict__ A,
                                               const __bf16* __restrict__ W,
                                               float* __restrict__ out) {
  __shared__ __align__(16) __bf16 As[2 * 128 * 32];  // 16KB
  __shared__ __align__(16) __bf16 Bs[2 * 128 * 32];  // 16KB

  const int tid = threadIdx.x;
  const int wv = tid >> 6;
  const int lane = tid & 63;
  const int mb = blockIdx.x & 63;
  const int nb = blockIdx.x >> 6;
  const int m0 = mb * 128;
  const int n0 = nb * 128;
  const int wr = wv & 1;   // wave row (m)
  const int wc = wv >> 1;  // wave col (n)

  // staging: wave wv covers rows [wv*32, wv*32+32); instr stages 16 rows x 32 cols
  const int srow = lane >> 2;          // 0..15
  const int scol = (lane & 3) * 8;     // 0,8,16,24
  const __bf16* gA = A + (size_t)(m0 + wv * 32 + srow) * KDIM + scol;
  const __bf16* gB = W + (size_t)(n0 + wv * 32 + srow) * KDIM + scol;
  __bf16* lA = As + wv * 1024;
  __bf16* lB = Bs + wv * 1024;

  // fragment LDS offsets (within one 128x32 sub-tile)
  const int mrow = lane & 15;
  const int quad = lane >> 4;
  int aoff[4], boff[4];
#pragma unroll
  for (int mt = 0; mt < 4; ++mt) aoff[mt] = (wr * 64 + mt * 16 + mrow) * 32 + quad * 8;
#pragma unroll
  for (int nt = 0; nt < 4; ++nt) boff[nt] = (wc * 64 + nt * 16 + mrow) * 32 + quad * 8;

  f32x4 acc[4][4];
  const f32x4 zero = {0.f, 0.f, 0.f, 0.f};
#pragma unroll
  for (int mt = 0; mt < 4; ++mt)
#pragma unroll
    for (int nt = 0; nt < 4; ++nt) acc[mt][nt] = zero;

  for (int k0 = 0; k0 < KDIM; k0 += 64) {
    __syncthreads();
    // h=0 sub-tile (cols k0..k0+31)
    g2l16(gA + k0, lA);
    g2l16(gA + k0 + (size_t)16 * KDIM, lA + 512);
    g2l16(gB + k0, lB);
    g2l16(gB + k0 + (size_t)16 * KDIM, lB + 512);
    // h=1 sub-tile (cols k0+32..k0+63)
    g2l16(gA + k0 + 32, lA + 4096);
    g2l16(gA + k0 + 32 + (size_t)16 * KDIM, lA + 4096 + 512);
    g2l16(gB + k0 + 32, lB + 4096);
    g2l16(gB + k0 + 32 + (size_t)16 * KDIM, lB + 4096 + 512);
    __syncthreads();

    bf16x8 af[2][4], bfr[2][4];
#pragma unroll
    for (int h = 0; h < 2; ++h) {
#pragma unroll
      for (int mt = 0; mt < 4; ++mt) af[h][mt] = *(const bf16x8*)(As + h * 4096 + aoff[mt]);
#pragma unroll
      for (int nt = 0; nt < 4; ++nt) bfr[h][nt] = *(const bf16x8*)(Bs + h * 4096 + boff[nt]);
    }
#pragma unroll
    for (int h = 0; h < 2; ++h)
#pragma unroll
      for (int mt = 0; mt < 4; ++mt)
#pragma unroll
        for (int nt = 0; nt < 4; ++nt)
          acc[mt][nt] = __builtin_amdgcn_mfma_f32_16x16x32_bf16(af[h][mt], bfr[h][nt],
                                                                acc[mt][nt], 0, 0, 0);
  }

  // epilogue: C/D layout col = lane&15, row = quad*4 + reg
#pragma unroll
  for (int mt = 0; mt < 4; ++mt) {
#pragma unroll
    for (int nt = 0; nt < 4; ++nt) {
      const int col = n0 + wc * 64 + nt * 16 + mrow;
      const int rbase = m0 + wr * 64 + mt * 16 + quad * 4;
#pragma unroll
      for (int r = 0; r < 4; ++r)
        out[(size_t)(rbase + r) * OUT_F + col] = acc[mt][nt][r];
    }
  }
}

// ---------------------------------------------------------------------------
extern "C" void kernel_launch(void* const* d_in, const int* in_sizes, int n_in,
                              void* d_out, int out_size, void* d_ws, size_t ws_size,
                              hipStream_t stream) {
  const float* x  = (const float*)d_in[0];
  // d_in[1] = grid: uniform linspace, folded into closed-form basis (unused)
  const float* bw = (const float*)d_in[2];  // [OUT_F, IN_F]
  const float* sw = (const float*)d_in[3];  // [IN_F, 8, OUT_F]
  const float* sc = (const float*)d_in[4];  // [IN_F, OUT_F]
  float* out = (float*)d_out;

  __bf16* Wt = (__bf16*)d_ws;                                    // [OUT_F][KDIM] 18.9 MB
  __bf16* Ab = (__bf16*)((char*)d_ws +
                         (size_t)OUT_F * KDIM * sizeof(__bf16)); // [BATCH][KDIM] 151 MB

  build_w<<<1024, 256, 0, stream>>>(bw, sw, sc, Wt);
  build_a<<<BATCH, 256, 0, stream>>>(x, Ab);
  gemm_bt<<<(BATCH / 128) * (OUT_F / 128), 256, 0, stream>>>(Ab, Wt, out);
}

// Round 6
// 317.358 us; speedup vs baseline: 1.5735x; 1.5735x over previous
//
#include <hip/hip_runtime.h>
#include <cstdint>
#include <cstddef>

#define BATCH 8192
#define IN_F 1024
#define OUT_F 1024
#define NSPL 9               // 1 base channel + 8 spline basis channels
#define KDIM (IN_F * NSPL)   // 9216
// K-ordering is PLANAR: k = r*1024 + i  (A and Wt agree; GEMM is
// permutation-agnostic as long as the two sides match).

typedef __bf16 bf16x8 __attribute__((ext_vector_type(8)));
typedef __bf16 bf16x4 __attribute__((ext_vector_type(4)));
typedef float f32x4 __attribute__((ext_vector_type(4)));

// async global->LDS, 16B/lane; LDS dest is wave-uniform base + lane*16
__device__ __forceinline__ void g2l16(const void* g, void* l) {
  __builtin_amdgcn_global_load_lds(
      (__attribute__((address_space(1))) void*)(g),
      (__attribute__((address_space(3))) void*)(l),
      16, 0, 0);
}

// ---------------------------------------------------------------------------
// Kernel 1: combined weight, planar: Wt[o][r*1024+i] bf16.
//   r=0: base_weight[o][i]; r=1..8: spline_weight[i][r-1][o]*spline_scaler[i][o]
// 64o x 16i LDS tile -> coalesced 256B input bursts; writes in 32B segments.
// ---------------------------------------------------------------------------
__global__ __launch_bounds__(256) void build_w(const float* __restrict__ bw,
                                               const float* __restrict__ sw,
                                               const float* __restrict__ sc,
                                               __bf16* __restrict__ Wt) {
  __shared__ float s_sw[16 * 8 * 64];  // [i][r][oo] 32KB
  __shared__ float s_sc[16 * 64];      // [i][oo]     4KB
  __shared__ float s_bw[64 * 16];      // [oo][i]     4KB
  const int tid = threadIdx.x;
  const int o0 = (blockIdx.x & 15) * 64;
  const int i0 = (blockIdx.x >> 4) * 16;

#pragma unroll
  for (int it = 0; it < 32; ++it) {   // sw: 8192 floats
    const int t = it * 256 + tid;
    const int i = t >> 9, r = (t >> 6) & 7, oo = t & 63;
    s_sw[t] = sw[((size_t)(i0 + i) * 8 + r) * OUT_F + o0 + oo];
  }
#pragma unroll
  for (int it = 0; it < 4; ++it) {    // sc: 1024 floats
    const int t = it * 256 + tid;
    const int i = t >> 6, oo = t & 63;
    s_sc[t] = sc[(size_t)(i0 + i) * OUT_F + o0 + oo];
  }
#pragma unroll
  for (int it = 0; it < 4; ++it) {    // bw: 1024 floats
    const int t = it * 256 + tid;
    const int oo = t >> 4, ii = t & 15;
    s_bw[t] = bw[(size_t)(o0 + oo) * IN_F + i0 + ii];
  }
  __syncthreads();

  // thread t: oo = t>>2, ig = (t&3)*4 -> 4 consecutive i's; 4 lanes = 32B contiguous
  const int oo = tid >> 2;
  const int ig = (tid & 3) * 4;
  __bf16* orow = Wt + (size_t)(o0 + oo) * KDIM;

  {  // r=0 plane: base weight
    bf16x4 v;
#pragma unroll
    for (int e = 0; e < 4; ++e) v[e] = (__bf16)s_bw[oo * 16 + ig + e];
    *(bf16x4*)(orow + i0 + ig) = v;
  }
#pragma unroll
  for (int r = 0; r < 8; ++r) {  // spline planes
    bf16x4 v;
#pragma unroll
    for (int e = 0; e < 4; ++e) {
      const int i = ig + e;
      v[e] = (__bf16)(s_sw[i * 512 + r * 64 + oo] * s_sc[i * 64 + oo]);
    }
    *(bf16x4*)(orow + (r + 1) * 1024 + i0 + ig) = v;
  }
}

// ---------------------------------------------------------------------------
// Kernel 2: augmented activations, planar: A[b][r*1024+i] bf16.
//   r=0: silu(x); r=1..8: closed-form uniform cubic B-spline basis.
// BRANCHLESS SELECT SCATTER: round-5 version indexed a register array with
// runtime j0 -> compiler lowered it to scratch (private memory), ~300MB of
// hidden traffic. Here every array index is a compile-time constant after
// unrolling; plane j's weight is picked by cndmask chain on d = j - cell + 3
// (cell=j+3 -> b0 ... cell=j -> b3, zero outside). Pure VGPR, no LDS.
// ---------------------------------------------------------------------------
__global__ __launch_bounds__(256) void build_a(const float* __restrict__ x,
                                               __bf16* __restrict__ A) {
  const int b = blockIdx.x;
  const int tid = threadIdx.x;
  const int i0 = tid * 4;
  const float4 v4 = ((const float4*)(x + (size_t)b * IN_F))[tid];
  const float vs[4] = {v4.x, v4.y, v4.z, v4.w};
  __bf16* dst = A + (size_t)b * KDIM;

  // plane 0: silu
  {
    bf16x4 s;
#pragma unroll
    for (int e = 0; e < 4; ++e) {
      const float v = vs[e];
      s[e] = (__bf16)(v / (1.f + __expf(-v)));
    }
    *(bf16x4*)(dst + i0) = s;  // 8B/lane, coalesced
  }

  // per-element cell + the 4 active basis values (constant-indexed arrays)
  float c0[4], c1[4], c2[4], c3[4];
  int cel[4];
#pragma unroll
  for (int e = 0; e < 4; ++e) {
    const float p = (vs[e] + 2.2f) * 2.5f;  // knots -2.2 + 0.4j, h=0.4
    const float fc = floorf(p);
    cel[e] = (int)fc;
    const float t = p - fc;
    const float t2 = t * t, t3 = t2 * t, omt = 1.f - t;
    c0[e] = (1.f / 6.f) * omt * omt * omt;                        // cell = j+3
    c1[e] = (1.f / 6.f) * (3.f * t3 - 6.f * t2 + 4.f);            // cell = j+2
    c2[e] = (1.f / 6.f) * (-3.f * t3 + 3.f * t2 + 3.f * t + 1.f); // cell = j+1
    c3[e] = (1.f / 6.f) * t3;                                     // cell = j
  }

#pragma unroll
  for (int j = 0; j < 8; ++j) {
    bf16x4 v;
#pragma unroll
    for (int e = 0; e < 4; ++e) {
      const int d = j - cel[e] + 3;
      const float w = (d == 0) ? c0[e]
                    : (d == 1) ? c1[e]
                    : (d == 2) ? c2[e]
                    : (d == 3) ? c3[e]
                               : 0.f;
      v[e] = (__bf16)w;
    }
    *(bf16x4*)(dst + (j + 1) * 1024 + i0) = v;  // 8B/lane, coalesced
  }
}

// ---------------------------------------------------------------------------
// Kernel 3 (round-3 structure, unchanged): GEMM
// out[8192][1024] = A[8192][9216] * Wt[1024][9216]^T; BK=64 as two proven
// 128x32 sub-tiles; 128x128 tile, 4 waves, 4x4 mfma 16x16x32 bf16.
// Occupancy is register-capped at 8 waves/CU (64 AGPR acc + 88 VGPR), so
// split-K / more blocks don't help (round-4 evidence).
// ---------------------------------------------------------------------------
__global__ __launch_bounds__(256) void gemm_bt(const __bf16* __restrict__ A,
                                               const __bf16* __restrict__ W,
                                               float* __restrict__ out) {
  __shared__ __align__(16) __bf16 As[2 * 128 * 32];  // 16KB
  __shared__ __align__(16) __bf16 Bs[2 * 128 * 32];  // 16KB

  const int tid = threadIdx.x;
  const int wv = tid >> 6;
  const int lane = tid & 63;
  const int mb = blockIdx.x & 63;
  const int nb = blockIdx.x >> 6;
  const int m0 = mb * 128;
  const int n0 = nb * 128;
  const int wr = wv & 1;   // wave row (m)
  const int wc = wv >> 1;  // wave col (n)

  // staging: wave wv covers rows [wv*32, wv*32+32); instr stages 16 rows x 32 cols
  const int srow = lane >> 2;          // 0..15
  const int scol = (lane & 3) * 8;     // 0,8,16,24
  const __bf16* gA = A + (size_t)(m0 + wv * 32 + srow) * KDIM + scol;
  const __bf16* gB = W + (size_t)(n0 + wv * 32 + srow) * KDIM + scol;
  __bf16* lA = As + wv * 1024;
  __bf16* lB = Bs + wv * 1024;

  // fragment LDS offsets (within one 128x32 sub-tile)
  const int mrow = lane & 15;
  const int quad = lane >> 4;
  int aoff[4], boff[4];
#pragma unroll
  for (int mt = 0; mt < 4; ++mt) aoff[mt] = (wr * 64 + mt * 16 + mrow) * 32 + quad * 8;
#pragma unroll
  for (int nt = 0; nt < 4; ++nt) boff[nt] = (wc * 64 + nt * 16 + mrow) * 32 + quad * 8;

  f32x4 acc[4][4];
  const f32x4 zero = {0.f, 0.f, 0.f, 0.f};
#pragma unroll
  for (int mt = 0; mt < 4; ++mt)
#pragma unroll
    for (int nt = 0; nt < 4; ++nt) acc[mt][nt] = zero;

  for (int k0 = 0; k0 < KDIM; k0 += 64) {
    __syncthreads();
    // h=0 sub-tile (cols k0..k0+31)
    g2l16(gA + k0, lA);
    g2l16(gA + k0 + (size_t)16 * KDIM, lA + 512);
    g2l16(gB + k0, lB);
    g2l16(gB + k0 + (size_t)16 * KDIM, lB + 512);
    // h=1 sub-tile (cols k0+32..k0+63)
    g2l16(gA + k0 + 32, lA + 4096);
    g2l16(gA + k0 + 32 + (size_t)16 * KDIM, lA + 4096 + 512);
    g2l16(gB + k0 + 32, lB + 4096);
    g2l16(gB + k0 + 32 + (size_t)16 * KDIM, lB + 4096 + 512);
    __syncthreads();

    bf16x8 af[2][4], bfr[2][4];
#pragma unroll
    for (int h = 0; h < 2; ++h) {
#pragma unroll
      for (int mt = 0; mt < 4; ++mt) af[h][mt] = *(const bf16x8*)(As + h * 4096 + aoff[mt]);
#pragma unroll
      for (int nt = 0; nt < 4; ++nt) bfr[h][nt] = *(const bf16x8*)(Bs + h * 4096 + boff[nt]);
    }
#pragma unroll
    for (int h = 0; h < 2; ++h)
#pragma unroll
      for (int mt = 0; mt < 4; ++mt)
#pragma unroll
        for (int nt = 0; nt < 4; ++nt)
          acc[mt][nt] = __builtin_amdgcn_mfma_f32_16x16x32_bf16(af[h][mt], bfr[h][nt],
                                                                acc[mt][nt], 0, 0, 0);
  }

  // epilogue: C/D layout col = lane&15, row = quad*4 + reg
#pragma unroll
  for (int mt = 0; mt < 4; ++mt) {
#pragma unroll
    for (int nt = 0; nt < 4; ++nt) {
      const int col = n0 + wc * 64 + nt * 16 + mrow;
      const int rbase = m0 + wr * 64 + mt * 16 + quad * 4;
#pragma unroll
      for (int r = 0; r < 4; ++r)
        out[(size_t)(rbase + r) * OUT_F + col] = acc[mt][nt][r];
    }
  }
}

// ---------------------------------------------------------------------------
extern "C" void kernel_launch(void* const* d_in, const int* in_sizes, int n_in,
                              void* d_out, int out_size, void* d_ws, size_t ws_size,
                              hipStream_t stream) {
  const float* x  = (const float*)d_in[0];
  // d_in[1] = grid: uniform linspace, folded into closed-form basis (unused)
  const float* bw = (const float*)d_in[2];  // [OUT_F, IN_F]
  const float* sw = (const float*)d_in[3];  // [IN_F, 8, OUT_F]
  const float* sc = (const float*)d_in[4];  // [IN_F, OUT_F]
  float* out = (float*)d_out;

  __bf16* Wt = (__bf16*)d_ws;                                    // [OUT_F][KDIM] 18.9 MB
  __bf16* Ab = (__bf16*)((char*)d_ws +
                         (size_t)OUT_F * KDIM * sizeof(__bf16)); // [BATCH][KDIM] 151 MB

  build_w<<<1024, 256, 0, stream>>>(bw, sw, sc, Wt);
  build_a<<<BATCH, 256, 0, stream>>>(x, Ab);
  gemm_bt<<<(BATCH / 128) * (OUT_F / 128), 256, 0, stream>>>(Ab, Wt, out);
}